// Round 1
// baseline (314.410 us; speedup 1.0000x reference)
//
#include <hip/hip_runtime.h>

#define BB 4
#define CC 3
#define HH 384
#define WW 384
#define FF 5
#define KK 25   // FF*FF
#define HW (HH*WW)

__global__ __launch_bounds__(256) void dsepconv_kernel(
    const float* __restrict__ inp,
    const float* __restrict__ vert,
    const float* __restrict__ horiz,
    const float* __restrict__ offx,
    const float* __restrict__ offy,
    const float* __restrict__ mask,
    float* __restrict__ out)
{
    int idx = blockIdx.x * blockDim.x + threadIdx.x;
    if (idx >= BB * HW) return;
    int x = idx % WW;
    int y = (idx / WW) % HH;
    int b = idx / HW;
    int planeoff = y * WW + x;

    // hoist the 5 vertical / 5 horizontal filter weights
    float v[FF], hz[FF];
#pragma unroll
    for (int f = 0; f < FF; ++f) {
        v[f]  = vert [(b * FF + f) * HW + planeoff];
        hz[f] = horiz[(b * FF + f) * HW + planeoff];
    }

    const float* in0 = inp + (size_t)b * CC * HW;
    const float* in1 = in0 + HW;
    const float* in2 = in1 + HW;

    float acc0 = 0.f, acc1 = 0.f, acc2 = 0.f;

    const float fy = (float)y;
    const float fx = (float)x;

    for (int ki = 0; ki < FF; ++ki) {
        float vki = v[ki];
        float dy  = fy + (float)(ki - 2);
        const float* ox_p = offx + (size_t)(b * KK + ki * FF) * HW + planeoff;
        const float* oy_p = offy + (size_t)(b * KK + ki * FF) * HW + planeoff;
        const float* m_p  = mask + (size_t)(b * KK + ki * FF) * HW + planeoff;
#pragma unroll
        for (int kj = 0; kj < FF; ++kj) {
            float ox = ox_p[kj * HW];
            float oy = oy_p[kj * HW];
            float m  = m_p [kj * HW];
            float wt = vki * hz[kj] * m;

            float py = oy + dy;
            float px = ox + fx + (float)(kj - 2);
            py = fminf(fmaxf(py, 0.f), (float)(HH - 1));
            px = fminf(fmaxf(px, 0.f), (float)(WW - 1));
            float y0f = floorf(py);
            float x0f = floorf(px);
            float wy = py - y0f;
            float wx = px - x0f;
            int y0 = (int)y0f;
            int x0 = (int)x0f;
            int y1 = min(y0 + 1, HH - 1);
            int x1 = min(x0 + 1, WW - 1);

            float w00 = (1.f - wy) * (1.f - wx);
            float w01 = (1.f - wy) * wx;
            float w10 = wy * (1.f - wx);
            float w11 = wy * wx;

            int i00 = y0 * WW + x0;
            int i01 = y0 * WW + x1;
            int i10 = y1 * WW + x0;
            int i11 = y1 * WW + x1;

            float s0 = in0[i00] * w00 + in0[i01] * w01 + in0[i10] * w10 + in0[i11] * w11;
            float s1 = in1[i00] * w00 + in1[i01] * w01 + in1[i10] * w10 + in1[i11] * w11;
            float s2 = in2[i00] * w00 + in2[i01] * w01 + in2[i10] * w10 + in2[i11] * w11;

            acc0 += wt * s0;
            acc1 += wt * s1;
            acc2 += wt * s2;
        }
    }

    out[(b * CC + 0) * HW + planeoff] = acc0;
    out[(b * CC + 1) * HW + planeoff] = acc1;
    out[(b * CC + 2) * HW + planeoff] = acc2;
}

extern "C" void kernel_launch(void* const* d_in, const int* in_sizes, int n_in,
                              void* d_out, int out_size, void* d_ws, size_t ws_size,
                              hipStream_t stream) {
    const float* inp   = (const float*)d_in[0];
    const float* vert  = (const float*)d_in[1];
    const float* horiz = (const float*)d_in[2];
    const float* offx  = (const float*)d_in[3];
    const float* offy  = (const float*)d_in[4];
    const float* mask  = (const float*)d_in[5];
    float* out = (float*)d_out;

    int total = BB * HW;
    dim3 block(256);
    dim3 grid((total + 255) / 256);
    dsepconv_kernel<<<grid, block, 0, stream>>>(inp, vert, horiz, offx, offy, mask, out);
}